// Round 2
// baseline (293.808 us; speedup 1.0000x reference)
//
#include <hip/hip_runtime.h>

#define N 3072
#define D_IN 64
#define HID 128
#define NH 4
#define HD 32
#define NB 1024
#define ALPHA 0.2f
#define TD 0.1f
#define EPS 1e-5f
#define LOG2E 1.4426950408889634f
#define TSPLIT 4
#define JSPAN (N / TSPLIT)  /* 768 */
#define NCH (JSPAN / 64)    /* 12  */
#define PSTR 80             /* padded bf16 row stride for p tiles */

typedef unsigned int uint;
typedef unsigned short ushort;
typedef __attribute__((ext_vector_type(8))) __bf16 bf16x8;
typedef __attribute__((ext_vector_type(4))) float f32x4;

__device__ __forceinline__ ushort f2bf(float f) {
  union { float f; uint u; } c; c.f = f;
  uint u = c.u;
  return (ushort)((u + 0x7FFFu + ((u >> 16) & 1u)) >> 16);
}

// ---------------- prep: global max of tmat, per-row deg0 flag ----------------
__global__ __launch_bounds__(256) void k_prep(const float* __restrict__ tmat,
                                              const float* __restrict__ adj,
                                              uint* __restrict__ tmax_u,
                                              uint* __restrict__ deg0) {
  int i = blockIdx.x;
  int t = threadIdx.x;
  const float* tr = tmat + (size_t)i * N;
  const float* ar = adj + (size_t)i * N;
  float mx = 0.f, sm = 0.f;
  for (int j = t; j < N; j += 256) { mx = fmaxf(mx, tr[j]); sm += ar[j]; }
  for (int o = 32; o > 0; o >>= 1) { mx = fmaxf(mx, __shfl_xor(mx, o)); sm += __shfl_xor(sm, o); }
  __shared__ float smx[4], ssm[4];
  int w = t >> 6, l = t & 63;
  if (l == 0) { smx[w] = mx; ssm[w] = sm; }
  __syncthreads();
  if (t == 0) {
    float m2 = fmaxf(fmaxf(smx[0], smx[1]), fmaxf(smx[2], smx[3]));
    float s2 = ssm[0] + ssm[1] + ssm[2] + ssm[3];
    deg0[i] = (s2 == 0.f) ? 1u : 0u;
    atomicMax(tmax_u, __float_as_uint(m2));
  }
}

// ---------------- struct = topic_emb @ Ws + bs ----------------
__global__ __launch_bounds__(128) void k_struct(const float* __restrict__ emb,
                                                const float* __restrict__ Ws,
                                                const float* __restrict__ bs,
                                                float* __restrict__ x0) {
  int n = blockIdx.x, c = threadIdx.x;
  __shared__ float es_[D_IN];
  if (c < D_IN) es_[c] = emb[n * D_IN + c];
  __syncthreads();
  float acc = bs[c];
#pragma unroll
  for (int i = 0; i < D_IN; i++) acc += es_[i] * Ws[i * HID + c];
  x0[(size_t)n * HID + c] = acc;
}

// ---------------- h = x @ Wcat ; es/ed ; hT (bf16) ----------------
__global__ __launch_bounds__(256) void k_h(const float* __restrict__ x,
                                           const float* __restrict__ gW,
                                           const float* __restrict__ gA,
                                           ushort* __restrict__ hT,
                                           float* __restrict__ es,
                                           float* __restrict__ ed) {
  int n0 = blockIdx.x * 16;
  int t = threadIdx.x;
  __shared__ float xs[16][HID];
  __shared__ float hs[16][HID];
  for (int k = t; k < 16 * HID; k += 256) xs[k >> 7][k & 127] = x[(size_t)n0 * HID + k];
  __syncthreads();
  int c = t & 127, rh = t >> 7;
  const float* Wc = gW + (c >> 5) * (HID * HD) + (c & 31);
  float acc[8];
#pragma unroll
  for (int r8 = 0; r8 < 8; r8++) acc[r8] = 0.f;
  for (int i = 0; i < HID; i++) {
    float wv = Wc[i * HD];
#pragma unroll
    for (int r8 = 0; r8 < 8; r8++) acc[r8] += xs[rh + 2 * r8][i] * wv;
  }
#pragma unroll
  for (int r8 = 0; r8 < 8; r8++) hs[rh + 2 * r8][c] = acc[r8];
  __syncthreads();
  if (t < 128) {
    int r = t >> 3, h_ = (t >> 1) & 3, sd = t & 1;
    const float* av = gA + h_ * (2 * HD) + sd * HD;
    float d = 0.f;
#pragma unroll
    for (int k = 0; k < HD; k++) d += hs[r][h_ * HD + k] * av[k];
    (sd ? ed : es)[h_ * N + n0 + r] = d;
  }
  {
    int half = t >> 7;
    ushort pk[8];
#pragma unroll
    for (int r = 0; r < 8; r++) pk[r] = f2bf(hs[half * 8 + r][c]);
    uint4 v;
    v.x = (uint)pk[0] | ((uint)pk[1] << 16);
    v.y = (uint)pk[2] | ((uint)pk[3] << 16);
    v.z = (uint)pk[4] | ((uint)pk[5] << 16);
    v.w = (uint)pk[6] | ((uint)pk[7] << 16);
    *(uint4*)(&hT[(size_t)c * N + n0 + half * 8]) = v;
  }
}

// ---------------- fused score + PV (flash-style, no max needed) ----------------
__global__ __launch_bounds__(256) void k_att(const float* __restrict__ tmat,
                                             const float* __restrict__ adj,
                                             const ushort* __restrict__ hT,
                                             const float* __restrict__ es,
                                             const float* __restrict__ ed,
                                             const uint* __restrict__ deg0,
                                             const uint* __restrict__ tmax_u,
                                             float* __restrict__ o_part,
                                             float* __restrict__ s_part) {
  __shared__ __align__(16) ushort ps[NH][16][PSTR];
  int tid = threadIdx.x;
  int ib = blockIdx.x * 16;
  int sp = blockIdx.y;
  int jb0 = sp * JSPAN;
  float tmax = __uint_as_float(*tmax_u);

  int jl = tid & 31;  // j-pair index (2 j's per thread)
  int ig = tid >> 5;  // 0..7 row group
  float esr[2][NH];
  uint dg[2];
#pragma unroll
  for (int p = 0; p < 2; p++) {
    int i = ib + ig + 8 * p;
    dg[p] = deg0[i];
#pragma unroll
    for (int h_ = 0; h_ < NH; h_++) esr[p][h_] = es[h_ * N + i];
  }

  int wv = tid >> 6;  // wave id == head
  int ln = tid & 63;
  f32x4 acc0 = {0.f, 0.f, 0.f, 0.f}, acc1 = {0.f, 0.f, 0.f, 0.f};
  float sacc[2][NH];
#pragma unroll
  for (int p = 0; p < 2; p++)
#pragma unroll
    for (int h_ = 0; h_ < NH; h_++) sacc[p][h_] = 0.f;

  const float c1 = TD * LOG2E;
  for (int ch = 0; ch < NCH; ch++) {
    int jb = jb0 + ch * 64;
    // ---- score phase: p[head][16][64] (bf16) into LDS ----
#pragma unroll
    for (int p = 0; p < 2; p++) {
      int i = ib + ig + 8 * p;
      int j0 = jb + 2 * jl;
      float2 t2 = *(const float2*)&tmat[(size_t)i * N + j0];
      float2 a2 = *(const float2*)&adj[(size_t)i * N + j0];
      float tw0 = exp2f(c1 * (t2.x - tmax));
      float tw1 = exp2f(c1 * (t2.y - tmax));
#pragma unroll
      for (int h_ = 0; h_ < NH; h_++) {
        float2 edv = *(const float2*)&ed[h_ * N + j0];
        float e0 = esr[p][h_] + edv.x;
        float e1 = esr[p][h_] + edv.y;
        float l0 = fmaxf(e0, 0.f) + ALPHA * fminf(e0, 0.f);
        float l1 = fmaxf(e1, 0.f) + ALPHA * fminf(e1, 0.f);
        float p0 = (a2.x != 0.f) ? exp2f(l0 * tw0 * LOG2E) : 0.f;
        float p1 = (a2.y != 0.f) ? exp2f(l1 * tw1 * LOG2E) : 0.f;
        if (dg[p]) { p0 = 1.f; p1 = 1.f; }
        sacc[p][h_] += p0 + p1;
        uint pk = (uint)f2bf(p0) | ((uint)f2bf(p1) << 16);
        *(uint*)&ps[h_][ig + 8 * p][2 * jl] = pk;
      }
    }
    __syncthreads();
    // ---- MFMA phase: wave wv = head wv, two 16x16 col tiles ----
    {
      const ushort* hTb = hT + (size_t)(wv * HD) * N + jb;
      int r = ln & 15, g = ln >> 4;
#pragma unroll
      for (int ks = 0; ks < 2; ks++) {
        bf16x8 afr = *(const bf16x8*)&ps[wv][r][ks * 32 + g * 8];
        const ushort* b0p = hTb + (size_t)r * N + ks * 32 + g * 8;
        const ushort* b1p = hTb + (size_t)(16 + r) * N + ks * 32 + g * 8;
        bf16x8 b0 = *(const bf16x8*)b0p;
        bf16x8 b1 = *(const bf16x8*)b1p;
        acc0 = __builtin_amdgcn_mfma_f32_16x16x32_bf16(afr, b0, acc0, 0, 0, 0);
        acc1 = __builtin_amdgcn_mfma_f32_16x16x32_bf16(afr, b1, acc1, 0, 0, 0);
      }
    }
    __syncthreads();
  }

  // ---- write s partials (reduce over 32 j-lanes) ----
#pragma unroll
  for (int p = 0; p < 2; p++)
#pragma unroll
    for (int h_ = 0; h_ < NH; h_++) {
      float v = sacc[p][h_];
      v += __shfl_xor(v, 16); v += __shfl_xor(v, 8);
      v += __shfl_xor(v, 4);  v += __shfl_xor(v, 2); v += __shfl_xor(v, 1);
      if (jl == 0) {
        int i = ib + ig + 8 * p;
        s_part[((size_t)sp * N + i) * NH + h_] = v;
      }
    }
  // ---- write o partials ----
  {
    int r = ln & 15, g = ln >> 4;
#pragma unroll
    for (int q = 0; q < 4; q++) {
      int i = ib + g * 4 + q;
      float* op = o_part + ((size_t)sp * N + i) * HID + wv * HD;
      op[r] = acc0[q];
      op[16 + r] = acc1[q];
    }
  }
}

// ---------------- combine splits, divide, ELU, LayerNorm ----------------
__global__ __launch_bounds__(128) void k_combine(const float* __restrict__ o_part,
                                                 const float* __restrict__ s_part,
                                                 const float* __restrict__ g,
                                                 const float* __restrict__ b,
                                                 float* __restrict__ xout) {
  int i = blockIdx.x, c = threadIdx.x;
  float o = 0.f, s = 0.f;
#pragma unroll
  for (int sp = 0; sp < TSPLIT; sp++) {
    o += o_part[((size_t)sp * N + i) * HID + c];
    s += s_part[((size_t)sp * N + i) * NH + (c >> 5)];
  }
  float v = o / s;
  v = v > 0.f ? v : expm1f(v);
  float sm = v, sq = v * v;
  for (int off = 32; off > 0; off >>= 1) { sm += __shfl_xor(sm, off); sq += __shfl_xor(sq, off); }
  __shared__ float s2[2][2];
  int w = c >> 6, l = c & 63;
  if (l == 0) { s2[w][0] = sm; s2[w][1] = sq; }
  __syncthreads();
  float tot = s2[0][0] + s2[1][0], totq = s2[0][1] + s2[1][1];
  float mu = tot / (float)HID;
  float var = totq / (float)HID - mu * mu;
  float rs = rsqrtf(var + EPS);
  xout[(size_t)i * HID + c] = (v - mu) * rs * g[c] + b[c];
}

// ---------------- final MLP + gather ----------------
__global__ __launch_bounds__(128) void k_final(const float* __restrict__ x,
                                               const int* __restrict__ tid,
                                               const float* __restrict__ attr,
                                               const float* __restrict__ Wa,
                                               const float* __restrict__ ba,
                                               const float* __restrict__ W1,
                                               const float* __restrict__ b1,
                                               const float* __restrict__ W2,
                                               const float* __restrict__ b2,
                                               float* __restrict__ out) {
  int bI = blockIdx.x, c = threadIdx.x;
  __shared__ float tf[HID];
  __shared__ float red[2];
  int id = tid[bI];
  float av = attr[bI];
  tf[c] = x[(size_t)id * HID + c] + av * Wa[c] + ba[c];
  __syncthreads();
  float acc = b1[c];
  for (int i = 0; i < HID; i++) acc += tf[i] * W1[i * HID + c];
  acc = fmaxf(acc, 0.f);
  float pr = acc * W2[c];
  for (int off = 32; off > 0; off >>= 1) pr += __shfl_xor(pr, off);
  int w = c >> 6, l = c & 63;
  if (l == 0) red[w] = pr;
  __syncthreads();
  if (c == 0) out[bI] = red[0] + red[1] + b2[0];
}

extern "C" void kernel_launch(void* const* d_in, const int* in_sizes, int n_in,
                              void* d_out, int out_size, void* d_ws, size_t ws_size,
                              hipStream_t stream) {
  (void)in_sizes; (void)n_in; (void)out_size; (void)ws_size;
  const int*   topic_ids = (const int*)d_in[0];
  const float* adj  = (const float*)d_in[1];
  const float* tmat = (const float*)d_in[2];
  const float* attr = (const float*)d_in[3];
  const float* emb  = (const float*)d_in[4];
  const float* Ws   = (const float*)d_in[5];
  const float* bs   = (const float*)d_in[6];
  const float* Wa   = (const float*)d_in[7];
  const float* ba   = (const float*)d_in[8];
  const float* gW   = (const float*)d_in[9];
  const float* gA   = (const float*)d_in[10];
  const float* lng  = (const float*)d_in[11];
  const float* lnb  = (const float*)d_in[12];
  const float* W1   = (const float*)d_in[13];
  const float* b1   = (const float*)d_in[14];
  const float* W2   = (const float*)d_in[15];
  const float* b2   = (const float*)d_in[16];

  char* ws = (char*)d_ws;
  size_t o = 0;
  auto alloc = [&](size_t bytes) { void* p = ws + o; o += (bytes + 255) & ~255ull; return p; };
  uint*   tmax_u = (uint*)alloc(4);
  uint*   deg0   = (uint*)alloc((size_t)N * 4);
  float*  X0     = (float*)alloc((size_t)N * HID * 4);
  float*  X1     = (float*)alloc((size_t)N * HID * 4);
  float*  X2     = (float*)alloc((size_t)N * HID * 4);
  ushort* hT     = (ushort*)alloc((size_t)HID * N * 2);
  float*  es     = (float*)alloc((size_t)NH * N * 4);
  float*  ed     = (float*)alloc((size_t)NH * N * 4);
  float*  o_part = (float*)alloc((size_t)TSPLIT * N * HID * 4);
  float*  s_part = (float*)alloc((size_t)TSPLIT * N * NH * 4);

  hipMemsetAsync(tmax_u, 0, 4, stream);
  k_prep<<<N, 256, 0, stream>>>(tmat, adj, tmax_u, deg0);
  k_struct<<<N, 128, 0, stream>>>(emb, Ws, bs, X0);

  const float* xin = X0;
  float* xouts[2] = {X1, X2};
  for (int l = 0; l < 2; l++) {
    k_h<<<N / 16, 256, 0, stream>>>(xin, gW + (size_t)l * NH * HID * HD,
                                    gA + (size_t)l * NH * 2 * HD, hT, es, ed);
    dim3 gr(N / 16, TSPLIT);
    k_att<<<gr, 256, 0, stream>>>(tmat, adj, hT, es, ed, deg0, tmax_u, o_part, s_part);
    k_combine<<<N, 128, 0, stream>>>(o_part, s_part, lng + l * HID, lnb + l * HID, xouts[l]);
    xin = xouts[l];
  }
  k_final<<<NB, 128, 0, stream>>>(X2, topic_ids, attr, Wa, ba, W1, b1, W2, b2, (float*)d_out);
}

// Round 3
// 255.621 us; speedup vs baseline: 1.1494x; 1.1494x over previous
//
#include <hip/hip_runtime.h>
#include <hip/hip_fp16.h>

#define N 3072
#define D_IN 64
#define HID 128
#define NH 4
#define HD 32
#define NB 1024
#define ALPHA 0.2f
#define TD 0.1f
#define EPS 1e-5f
#define LOG2E 1.4426950408889634f
#define TSPLIT 4
#define JSPAN (N / TSPLIT)  /* 768 */
#define NCH (JSPAN / 64)    /* 12  */
#define PSTR 80             /* padded bf16 row stride for p tiles */

typedef unsigned int uint;
typedef unsigned short ushort;
typedef __attribute__((ext_vector_type(8))) __bf16 bf16x8;
typedef __attribute__((ext_vector_type(4))) float f32x4;

__device__ __forceinline__ ushort f2bf(float f) {
  union { float f; uint u; } c; c.f = f;
  uint u = c.u;
  return (ushort)((u + 0x7FFFu + ((u >> 16) & 1u)) >> 16);
}

// ---------------- prep1: global max of tmat (float4 grid-stride) ----------------
// 9.4M floats = 2,359,296 float4 = 1024 blocks x 256 threads x 9 exactly.
__global__ __launch_bounds__(256) void k_prep1(const float4* __restrict__ tmat4,
                                               uint* __restrict__ tmax_u) {
  int g = blockIdx.x * 256 + threadIdx.x;
  float mx = 0.f;
#pragma unroll
  for (int k = 0; k < 9; k++) {
    float4 v = tmat4[g + k * 262144];
    mx = fmaxf(mx, fmaxf(fmaxf(v.x, v.y), fmaxf(v.z, v.w)));
  }
  for (int o = 32; o > 0; o >>= 1) mx = fmaxf(mx, __shfl_xor(mx, o));
  __shared__ float sm[4];
  if ((threadIdx.x & 63) == 0) sm[threadIdx.x >> 6] = mx;
  __syncthreads();
  if (threadIdx.x == 0) {
    float m = fmaxf(fmaxf(sm[0], sm[1]), fmaxf(sm[2], sm[3]));
    atomicMax(tmax_u, __float_as_uint(m));
  }
}

// ---------------- prep2: aw = adj ? fp16(tw*LOG2E) : 0 ; deg0 ----------------
// wave-per-row; per lane 12x (float4 tmat + float4 adj) -> ushort4 aw store.
__global__ __launch_bounds__(256) void k_prep2(const float* __restrict__ tmat,
                                               const float* __restrict__ adj,
                                               const uint* __restrict__ tmax_u,
                                               ushort* __restrict__ aw,
                                               uint* __restrict__ deg0) {
  int row = blockIdx.x * 4 + (threadIdx.x >> 6);
  int lane = threadIdx.x & 63;
  float tmax = __uint_as_float(*tmax_u);
  const float c1 = TD * LOG2E;
  const float4* tr = (const float4*)(tmat + (size_t)row * N);
  const float4* ar = (const float4*)(adj + (size_t)row * N);
  ushort* ao = aw + (size_t)row * N;
  float s = 0.f;
#pragma unroll
  for (int it = 0; it < 12; it++) {
    int c4 = lane + it * 64;  // float4 index within row
    float4 t4 = tr[c4];
    float4 a4 = ar[c4];
    s += a4.x + a4.y + a4.z + a4.w;
    float w0 = exp2f(c1 * (t4.x - tmax)) * LOG2E;
    float w1 = exp2f(c1 * (t4.y - tmax)) * LOG2E;
    float w2 = exp2f(c1 * (t4.z - tmax)) * LOG2E;
    float w3 = exp2f(c1 * (t4.w - tmax)) * LOG2E;
    ushort u0 = (a4.x != 0.f) ? __half_as_ushort(__float2half(w0)) : (ushort)0;
    ushort u1 = (a4.y != 0.f) ? __half_as_ushort(__float2half(w1)) : (ushort)0;
    ushort u2 = (a4.z != 0.f) ? __half_as_ushort(__float2half(w2)) : (ushort)0;
    ushort u3 = (a4.w != 0.f) ? __half_as_ushort(__float2half(w3)) : (ushort)0;
    uint2 pk;
    pk.x = (uint)u0 | ((uint)u1 << 16);
    pk.y = (uint)u2 | ((uint)u3 << 16);
    *(uint2*)(ao + c4 * 4) = pk;
  }
  for (int o = 32; o > 0; o >>= 1) s += __shfl_xor(s, o);
  if (lane == 0) deg0[row] = (s == 0.f) ? 1u : 0u;
}

// ---------------- struct = topic_emb @ Ws + bs ----------------
__global__ __launch_bounds__(128) void k_struct(const float* __restrict__ emb,
                                                const float* __restrict__ Ws,
                                                const float* __restrict__ bs,
                                                float* __restrict__ x0) {
  int n = blockIdx.x, c = threadIdx.x;
  __shared__ float es_[D_IN];
  if (c < D_IN) es_[c] = emb[n * D_IN + c];
  __syncthreads();
  float acc = bs[c];
#pragma unroll
  for (int i = 0; i < D_IN; i++) acc += es_[i] * Ws[i * HID + c];
  x0[(size_t)n * HID + c] = acc;
}

// ---------------- h = x @ Wcat ; es/ed ; hT (bf16) ----------------
__global__ __launch_bounds__(256) void k_h(const float* __restrict__ x,
                                           const float* __restrict__ gW,
                                           const float* __restrict__ gA,
                                           ushort* __restrict__ hT,
                                           float* __restrict__ es,
                                           float* __restrict__ ed) {
  int n0 = blockIdx.x * 16;
  int t = threadIdx.x;
  __shared__ float xs[16][HID];
  __shared__ float hs[16][HID];
  for (int k = t; k < 16 * HID; k += 256) xs[k >> 7][k & 127] = x[(size_t)n0 * HID + k];
  __syncthreads();
  int c = t & 127, rh = t >> 7;
  const float* Wc = gW + (c >> 5) * (HID * HD) + (c & 31);
  float acc[8];
#pragma unroll
  for (int r8 = 0; r8 < 8; r8++) acc[r8] = 0.f;
  for (int i = 0; i < HID; i++) {
    float wv = Wc[i * HD];
#pragma unroll
    for (int r8 = 0; r8 < 8; r8++) acc[r8] += xs[rh + 2 * r8][i] * wv;
  }
#pragma unroll
  for (int r8 = 0; r8 < 8; r8++) hs[rh + 2 * r8][c] = acc[r8];
  __syncthreads();
  if (t < 128) {
    int r = t >> 3, h_ = (t >> 1) & 3, sd = t & 1;
    const float* av = gA + h_ * (2 * HD) + sd * HD;
    float d = 0.f;
#pragma unroll
    for (int k = 0; k < HD; k++) d += hs[r][h_ * HD + k] * av[k];
    (sd ? ed : es)[h_ * N + n0 + r] = d;
  }
  {
    int half = t >> 7;
    ushort pk[8];
#pragma unroll
    for (int r = 0; r < 8; r++) pk[r] = f2bf(hs[half * 8 + r][c]);
    uint4 v;
    v.x = (uint)pk[0] | ((uint)pk[1] << 16);
    v.y = (uint)pk[2] | ((uint)pk[3] << 16);
    v.z = (uint)pk[4] | ((uint)pk[5] << 16);
    v.w = (uint)pk[6] | ((uint)pk[7] << 16);
    *(uint4*)(&hT[(size_t)c * N + n0 + half * 8]) = v;
  }
}

// ---------------- fused score + PV, double-buffered p tiles, 1 barrier/chunk ----------------
__global__ __launch_bounds__(256) void k_att(const ushort* __restrict__ aw,
                                             const ushort* __restrict__ hT,
                                             const float* __restrict__ es,
                                             const float* __restrict__ ed,
                                             const uint* __restrict__ deg0,
                                             float* __restrict__ o_part,
                                             float* __restrict__ s_part) {
  __shared__ __align__(16) ushort ps[2][NH][16][PSTR];
  int tid = threadIdx.x;
  int ib = blockIdx.x * 16;
  int sp = blockIdx.y;
  int jb0 = sp * JSPAN;

  int jl = tid & 31;  // j-pair index (2 j's per thread)
  int ig = tid >> 5;  // 0..7 row group
  float esr[2][NH];
  uint dg[2];
#pragma unroll
  for (int p = 0; p < 2; p++) {
    int i = ib + ig + 8 * p;
    dg[p] = deg0[i];
#pragma unroll
    for (int h_ = 0; h_ < NH; h_++) esr[p][h_] = es[h_ * N + i];
  }

  int wv = tid >> 6;  // wave id == head
  int ln = tid & 63;
  f32x4 acc0 = {0.f, 0.f, 0.f, 0.f}, acc1 = {0.f, 0.f, 0.f, 0.f};
  float sacc[2][NH];
#pragma unroll
  for (int p = 0; p < 2; p++)
#pragma unroll
    for (int h_ = 0; h_ < NH; h_++) sacc[p][h_] = 0.f;

  uint awv[2];
  float2 edv[NH];

  auto LOADS = [&](int ch) {
    int j0 = jb0 + ch * 64 + 2 * jl;
    awv[0] = *(const uint*)&aw[(size_t)(ib + ig) * N + j0];
    awv[1] = *(const uint*)&aw[(size_t)(ib + ig + 8) * N + j0];
#pragma unroll
    for (int h_ = 0; h_ < NH; h_++) edv[h_] = *(const float2*)&ed[h_ * N + j0];
  };
  auto COMPUTE = [&](int buf) {
#pragma unroll
    for (int p = 0; p < 2; p++) {
      float a0 = __half2float(__ushort_as_half((ushort)(awv[p] & 0xFFFFu)));
      float a1 = __half2float(__ushort_as_half((ushort)(awv[p] >> 16)));
#pragma unroll
      for (int h_ = 0; h_ < NH; h_++) {
        float e0 = esr[p][h_] + edv[h_].x;
        float e1 = esr[p][h_] + edv[h_].y;
        float l0 = fmaxf(e0, 0.f) + ALPHA * fminf(e0, 0.f);
        float l1 = fmaxf(e1, 0.f) + ALPHA * fminf(e1, 0.f);
        float p0 = (a0 != 0.f) ? exp2f(l0 * a0) : 0.f;
        float p1 = (a1 != 0.f) ? exp2f(l1 * a1) : 0.f;
        if (dg[p]) { p0 = 1.f; p1 = 1.f; }
        sacc[p][h_] += p0 + p1;
        uint pk = (uint)f2bf(p0) | ((uint)f2bf(p1) << 16);
        *(uint*)&ps[buf][h_][ig + 8 * p][2 * jl] = pk;
      }
    }
  };

  // prologue: chunk 0 into buf 0
  LOADS(0);
  COMPUTE(0);

  int r = ln & 15, g = ln >> 4;
  for (int ch = 0; ch < NCH; ch++) {
    __syncthreads();
    if (ch + 1 < NCH) LOADS(ch + 1);  // issue next-chunk loads before MFMA
    {
      int jb = jb0 + ch * 64;
      const ushort* hTb = hT + (size_t)(wv * HD) * N + jb;
      int buf = ch & 1;
#pragma unroll
      for (int ks = 0; ks < 2; ks++) {
        bf16x8 afr = *(const bf16x8*)&ps[buf][wv][r][ks * 32 + g * 8];
        const ushort* b0p = hTb + (size_t)r * N + ks * 32 + g * 8;
        const ushort* b1p = hTb + (size_t)(16 + r) * N + ks * 32 + g * 8;
        bf16x8 b0 = *(const bf16x8*)b0p;
        bf16x8 b1 = *(const bf16x8*)b1p;
        acc0 = __builtin_amdgcn_mfma_f32_16x16x32_bf16(afr, b0, acc0, 0, 0, 0);
        acc1 = __builtin_amdgcn_mfma_f32_16x16x32_bf16(afr, b1, acc1, 0, 0, 0);
      }
    }
    if (ch + 1 < NCH) COMPUTE((ch + 1) & 1);
  }

  // ---- write s partials (reduce over 32 j-lanes) ----
#pragma unroll
  for (int p = 0; p < 2; p++)
#pragma unroll
    for (int h_ = 0; h_ < NH; h_++) {
      float v = sacc[p][h_];
      v += __shfl_xor(v, 16); v += __shfl_xor(v, 8);
      v += __shfl_xor(v, 4);  v += __shfl_xor(v, 2); v += __shfl_xor(v, 1);
      if (jl == 0) {
        int i = ib + ig + 8 * p;
        s_part[((size_t)sp * N + i) * NH + h_] = v;
      }
    }
  // ---- write o partials ----
  {
#pragma unroll
    for (int q = 0; q < 4; q++) {
      int i = ib + g * 4 + q;
      float* op = o_part + ((size_t)sp * N + i) * HID + wv * HD;
      op[r] = acc0[q];
      op[16 + r] = acc1[q];
    }
  }
}

// ---------------- combine splits, divide, ELU, LayerNorm ----------------
__global__ __launch_bounds__(128) void k_combine(const float* __restrict__ o_part,
                                                 const float* __restrict__ s_part,
                                                 const float* __restrict__ g,
                                                 const float* __restrict__ b,
                                                 float* __restrict__ xout) {
  int i = blockIdx.x, c = threadIdx.x;
  float o = 0.f, s = 0.f;
#pragma unroll
  for (int sp = 0; sp < TSPLIT; sp++) {
    o += o_part[((size_t)sp * N + i) * HID + c];
    s += s_part[((size_t)sp * N + i) * NH + (c >> 5)];
  }
  float v = o / s;
  v = v > 0.f ? v : expm1f(v);
  float sm = v, sq = v * v;
  for (int off = 32; off > 0; off >>= 1) { sm += __shfl_xor(sm, off); sq += __shfl_xor(sq, off); }
  __shared__ float s2[2][2];
  int w = c >> 6, l = c & 63;
  if (l == 0) { s2[w][0] = sm; s2[w][1] = sq; }
  __syncthreads();
  float tot = s2[0][0] + s2[1][0], totq = s2[0][1] + s2[1][1];
  float mu = tot / (float)HID;
  float var = totq / (float)HID - mu * mu;
  float rs = rsqrtf(var + EPS);
  xout[(size_t)i * HID + c] = (v - mu) * rs * g[c] + b[c];
}

// ---------------- final MLP + gather ----------------
__global__ __launch_bounds__(128) void k_final(const float* __restrict__ x,
                                               const int* __restrict__ tid,
                                               const float* __restrict__ attr,
                                               const float* __restrict__ Wa,
                                               const float* __restrict__ ba,
                                               const float* __restrict__ W1,
                                               const float* __restrict__ b1,
                                               const float* __restrict__ W2,
                                               const float* __restrict__ b2,
                                               float* __restrict__ out) {
  int bI = blockIdx.x, c = threadIdx.x;
  __shared__ float tf[HID];
  __shared__ float red[2];
  int id = tid[bI];
  float av = attr[bI];
  tf[c] = x[(size_t)id * HID + c] + av * Wa[c] + ba[c];
  __syncthreads();
  float acc = b1[c];
  for (int i = 0; i < HID; i++) acc += tf[i] * W1[i * HID + c];
  acc = fmaxf(acc, 0.f);
  float pr = acc * W2[c];
  for (int off = 32; off > 0; off >>= 1) pr += __shfl_xor(pr, off);
  int w = c >> 6, l = c & 63;
  if (l == 0) red[w] = pr;
  __syncthreads();
  if (c == 0) out[bI] = red[0] + red[1] + b2[0];
}

extern "C" void kernel_launch(void* const* d_in, const int* in_sizes, int n_in,
                              void* d_out, int out_size, void* d_ws, size_t ws_size,
                              hipStream_t stream) {
  (void)in_sizes; (void)n_in; (void)out_size; (void)ws_size;
  const int*   topic_ids = (const int*)d_in[0];
  const float* adj  = (const float*)d_in[1];
  const float* tmat = (const float*)d_in[2];
  const float* attr = (const float*)d_in[3];
  const float* emb  = (const float*)d_in[4];
  const float* Ws   = (const float*)d_in[5];
  const float* bs   = (const float*)d_in[6];
  const float* Wa   = (const float*)d_in[7];
  const float* ba   = (const float*)d_in[8];
  const float* gW   = (const float*)d_in[9];
  const float* gA   = (const float*)d_in[10];
  const float* lng  = (const float*)d_in[11];
  const float* lnb  = (const float*)d_in[12];
  const float* W1   = (const float*)d_in[13];
  const float* b1   = (const float*)d_in[14];
  const float* W2   = (const float*)d_in[15];
  const float* b2   = (const float*)d_in[16];

  char* ws = (char*)d_ws;
  size_t o = 0;
  auto alloc = [&](size_t bytes) { void* p = ws + o; o += (bytes + 255) & ~255ull; return p; };
  uint*   tmax_u = (uint*)alloc(4);
  uint*   deg0   = (uint*)alloc((size_t)N * 4);
  float*  X0     = (float*)alloc((size_t)N * HID * 4);
  float*  X1     = (float*)alloc((size_t)N * HID * 4);
  float*  X2     = (float*)alloc((size_t)N * HID * 4);
  ushort* hT     = (ushort*)alloc((size_t)HID * N * 2);
  float*  es     = (float*)alloc((size_t)NH * N * 4);
  float*  ed     = (float*)alloc((size_t)NH * N * 4);
  float*  o_part = (float*)alloc((size_t)TSPLIT * N * HID * 4);
  float*  s_part = (float*)alloc((size_t)TSPLIT * N * NH * 4);
  ushort* aw     = (ushort*)alloc((size_t)N * N * 2);  // 18.9 MB, total ws ~31 MB

  hipMemsetAsync(tmax_u, 0, 4, stream);
  k_prep1<<<1024, 256, 0, stream>>>((const float4*)tmat, tmax_u);
  k_prep2<<<N / 4, 256, 0, stream>>>(tmat, adj, tmax_u, aw, deg0);
  k_struct<<<N, 128, 0, stream>>>(emb, Ws, bs, X0);

  const float* xin = X0;
  float* xouts[2] = {X1, X2};
  for (int l = 0; l < 2; l++) {
    k_h<<<N / 16, 256, 0, stream>>>(xin, gW + (size_t)l * NH * HID * HD,
                                    gA + (size_t)l * NH * 2 * HD, hT, es, ed);
    dim3 gr(N / 16, TSPLIT);
    k_att<<<gr, 256, 0, stream>>>(aw, hT, es, ed, deg0, o_part, s_part);
    k_combine<<<N, 128, 0, stream>>>(o_part, s_part, lng + l * HID, lnb + l * HID, xouts[l]);
    xin = xouts[l];
  }
  k_final<<<NB, 128, 0, stream>>>(X2, topic_ids, attr, Wa, ba, W1, b1, W2, b2, (float*)d_out);
}

// Round 6
// 248.974 us; speedup vs baseline: 1.1801x; 1.0267x over previous
//
#include <hip/hip_runtime.h>
#include <hip/hip_fp16.h>

#define N 3072
#define D_IN 64
#define HID 128
#define NH 4
#define HD 32
#define NB 1024
#define ALPHA 0.2f
#define TD 0.1f
#define EPS 1e-5f
#define LOG2E 1.4426950408889634f
#define TSPLIT 16
#define JSPAN (N / TSPLIT)  /* 192 */
#define NCH (JSPAN / 64)    /* 3   */
#define PSTR 72             /* padded bf16 row stride for p tiles */

typedef unsigned int uint;
typedef unsigned short ushort;
typedef __attribute__((ext_vector_type(8))) __bf16 bf16x8;
typedef __attribute__((ext_vector_type(4))) float f32x4;

__device__ __forceinline__ ushort f2bf(float f) {
  union { float f; uint u; } c; c.f = f;
  uint u = c.u;
  return (ushort)((u + 0x7FFFu + ((u >> 16) & 1u)) >> 16);
}

// ---------------- prep1: global max of tmat (float4 grid-stride) ----------------
__global__ __launch_bounds__(256) void k_prep1(const float4* __restrict__ tmat4,
                                               uint* __restrict__ tmax_u) {
  int g = blockIdx.x * 256 + threadIdx.x;
  float mx = 0.f;
#pragma unroll
  for (int k = 0; k < 9; k++) {
    float4 v = tmat4[g + k * 262144];
    mx = fmaxf(mx, fmaxf(fmaxf(v.x, v.y), fmaxf(v.z, v.w)));
  }
  for (int o = 32; o > 0; o >>= 1) mx = fmaxf(mx, __shfl_xor(mx, o));
  __shared__ float sm[4];
  if ((threadIdx.x & 63) == 0) sm[threadIdx.x >> 6] = mx;
  __syncthreads();
  if (threadIdx.x == 0) {
    float m = fmaxf(fmaxf(sm[0], sm[1]), fmaxf(sm[2], sm[3]));
    atomicMax(tmax_u, __float_as_uint(m));
  }
}

// ---------------- prep2: aw = adj ? fp16(tw*LOG2E) : 0 ; deg0 ----------------
__global__ __launch_bounds__(256) void k_prep2(const float* __restrict__ tmat,
                                               const float* __restrict__ adj,
                                               const uint* __restrict__ tmax_u,
                                               ushort* __restrict__ aw,
                                               uint* __restrict__ deg0) {
  int row = blockIdx.x * 4 + (threadIdx.x >> 6);
  int lane = threadIdx.x & 63;
  float tmax = __uint_as_float(*tmax_u);
  const float c1 = TD * LOG2E;
  const float4* tr = (const float4*)(tmat + (size_t)row * N);
  const float4* ar = (const float4*)(adj + (size_t)row * N);
  ushort* ao = aw + (size_t)row * N;
  float s = 0.f;
#pragma unroll
  for (int it = 0; it < 12; it++) {
    int c4 = lane + it * 64;
    float4 t4 = tr[c4];
    float4 a4 = ar[c4];
    s += a4.x + a4.y + a4.z + a4.w;
    float w0 = __builtin_amdgcn_exp2f(c1 * (t4.x - tmax)) * LOG2E;
    float w1 = __builtin_amdgcn_exp2f(c1 * (t4.y - tmax)) * LOG2E;
    float w2 = __builtin_amdgcn_exp2f(c1 * (t4.z - tmax)) * LOG2E;
    float w3 = __builtin_amdgcn_exp2f(c1 * (t4.w - tmax)) * LOG2E;
    ushort u0 = (a4.x != 0.f) ? __half_as_ushort(__float2half(w0)) : (ushort)0;
    ushort u1 = (a4.y != 0.f) ? __half_as_ushort(__float2half(w1)) : (ushort)0;
    ushort u2 = (a4.z != 0.f) ? __half_as_ushort(__float2half(w2)) : (ushort)0;
    ushort u3 = (a4.w != 0.f) ? __half_as_ushort(__float2half(w3)) : (ushort)0;
    uint2 pk;
    pk.x = (uint)u0 | ((uint)u1 << 16);
    pk.y = (uint)u2 | ((uint)u3 << 16);
    *(uint2*)(ao + c4 * 4) = pk;
  }
  for (int o = 32; o > 0; o >>= 1) s += __shfl_xor(s, o);
  if (lane == 0) deg0[row] = (s == 0.f) ? 1u : 0u;
}

// ---------------- struct = topic_emb @ Ws + bs ----------------
__global__ __launch_bounds__(128) void k_struct(const float* __restrict__ emb,
                                                const float* __restrict__ Ws,
                                                const float* __restrict__ bs,
                                                float* __restrict__ x0) {
  int n = blockIdx.x, c = threadIdx.x;
  __shared__ float es_[D_IN];
  if (c < D_IN) es_[c] = emb[n * D_IN + c];
  __syncthreads();
  float acc = bs[c];
#pragma unroll
  for (int i = 0; i < D_IN; i++) acc += es_[i] * Ws[i * HID + c];
  x0[(size_t)n * HID + c] = acc;
}

// ---------------- h = x @ Wcat ; es/ed ; hT (bf16). 8 rows/block, 384 blocks ----------------
__global__ __launch_bounds__(256) void k_h(const float* __restrict__ x,
                                           const float* __restrict__ gW,
                                           const float* __restrict__ gA,
                                           ushort* __restrict__ hT,
                                           float* __restrict__ es,
                                           float* __restrict__ ed) {
  int n0 = blockIdx.x * 8;
  int t = threadIdx.x;
  __shared__ float xs[8][HID];
  __shared__ float hs[8][HID];
  for (int k = t; k < 8 * HID; k += 256) xs[k >> 7][k & 127] = x[(size_t)n0 * HID + k];
  __syncthreads();
  int c = t & 127, rh = t >> 7;
  const float* Wc = gW + (c >> 5) * (HID * HD) + (c & 31);
  float acc[4] = {0.f, 0.f, 0.f, 0.f};
  for (int i = 0; i < HID; i++) {
    float wv = Wc[i * HD];
#pragma unroll
    for (int r4 = 0; r4 < 4; r4++) acc[r4] += xs[rh + 2 * r4][i] * wv;
  }
#pragma unroll
  for (int r4 = 0; r4 < 4; r4++) hs[rh + 2 * r4][c] = acc[r4];
  __syncthreads();
  if (t < 64) {
    int r = t >> 3, h_ = (t >> 1) & 3, sd = t & 1;
    const float* av = gA + h_ * (2 * HD) + sd * HD;
    float d = 0.f;
#pragma unroll
    for (int k = 0; k < HD; k++) d += hs[r][h_ * HD + k] * av[k];
    (sd ? ed : es)[h_ * N + n0 + r] = d;
  }
  {
    int half = t >> 7;
    ushort pk[4];
#pragma unroll
    for (int r = 0; r < 4; r++) pk[r] = f2bf(hs[half * 4 + r][c]);
    uint2 v;
    v.x = (uint)pk[0] | ((uint)pk[1] << 16);
    v.y = (uint)pk[2] | ((uint)pk[3] << 16);
    *(uint2*)(&hT[(size_t)c * N + n0 + half * 4]) = v;
  }
}

// ---------------- fused score + PV: 32 rows/block, TSPLIT=16, dbuf, 1 barrier/chunk ----------------
__global__ __launch_bounds__(256) void k_att(const ushort* __restrict__ aw,
                                             const ushort* __restrict__ hT,
                                             const float* __restrict__ es,
                                             const float* __restrict__ ed,
                                             const uint* __restrict__ deg0,
                                             float* __restrict__ o_part,
                                             float* __restrict__ s_part) {
  __shared__ __align__(16) ushort ps[2][NH][32][PSTR];
  int tid = threadIdx.x;
  int ib = blockIdx.x * 32;
  int sp = blockIdx.y;
  int jb0 = sp * JSPAN;

  int jl = tid & 31;  // j-pair index (2 j's per thread)
  int ig = tid >> 5;  // 0..7 row group; rows ig, ig+8, ig+16, ig+24
  float esr[4][NH];
  uint dg[4];
#pragma unroll
  for (int p = 0; p < 4; p++) {
    int i = ib + ig + 8 * p;
    dg[p] = deg0[i];
#pragma unroll
    for (int h_ = 0; h_ < NH; h_++) esr[p][h_] = es[h_ * N + i];
  }

  int wv = tid >> 6;  // wave id == head
  int ln = tid & 63;
  f32x4 acc00 = {0.f, 0.f, 0.f, 0.f}, acc01 = {0.f, 0.f, 0.f, 0.f};
  f32x4 acc10 = {0.f, 0.f, 0.f, 0.f}, acc11 = {0.f, 0.f, 0.f, 0.f};
  float sacc[4][NH];
#pragma unroll
  for (int p = 0; p < 4; p++)
#pragma unroll
    for (int h_ = 0; h_ < NH; h_++) sacc[p][h_] = 0.f;

  uint awv[4];
  float2 edv[NH];

  auto LOADS = [&](int ch) {
    int j0 = jb0 + ch * 64 + 2 * jl;
#pragma unroll
    for (int p = 0; p < 4; p++)
      awv[p] = *(const uint*)&aw[(size_t)(ib + ig + 8 * p) * N + j0];
#pragma unroll
    for (int h_ = 0; h_ < NH; h_++) edv[h_] = *(const float2*)&ed[h_ * N + j0];
  };
  auto COMPUTE = [&](int buf) {
#pragma unroll
    for (int p = 0; p < 4; p++) {
      float a0 = __half2float(__ushort_as_half((ushort)(awv[p] & 0xFFFFu)));
      float a1 = __half2float(__ushort_as_half((ushort)(awv[p] >> 16)));
#pragma unroll
      for (int h_ = 0; h_ < NH; h_++) {
        float e0 = esr[p][h_] + edv[h_].x;
        float e1 = esr[p][h_] + edv[h_].y;
        float l0 = fmaxf(e0, 0.f) + ALPHA * fminf(e0, 0.f);
        float l1 = fmaxf(e1, 0.f) + ALPHA * fminf(e1, 0.f);
        float p0 = __builtin_amdgcn_exp2f(l0 * a0);
        float p1 = __builtin_amdgcn_exp2f(l1 * a1);
        p0 = (a0 != 0.f) ? p0 : 0.f;
        p1 = (a1 != 0.f) ? p1 : 0.f;
        if (dg[p]) { p0 = 1.f; p1 = 1.f; }
        sacc[p][h_] += p0 + p1;
        // truncation pack (LN absorbs the tiny uniform scale; scatter == RNE's)
        uint pk = (__float_as_uint(p0) >> 16) | (__float_as_uint(p1) & 0xFFFF0000u);
        *(uint*)&ps[buf][h_][ig + 8 * p][2 * jl] = pk;
      }
    }
  };

  LOADS(0);
  COMPUTE(0);

  int r = ln & 15, g = ln >> 4;
  for (int ch = 0; ch < NCH; ch++) {
    __syncthreads();
    if (ch + 1 < NCH) LOADS(ch + 1);
    {
      int jb = jb0 + ch * 64;
      const ushort* hTb = hT + (size_t)(wv * HD) * N + jb;
      int buf = ch & 1;
#pragma unroll
      for (int ks = 0; ks < 2; ks++) {
        bf16x8 a0f = *(const bf16x8*)&ps[buf][wv][r][ks * 32 + g * 8];
        bf16x8 a1f = *(const bf16x8*)&ps[buf][wv][16 + r][ks * 32 + g * 8];
        bf16x8 b0 = *(const bf16x8*)(hTb + (size_t)r * N + ks * 32 + g * 8);
        bf16x8 b1 = *(const bf16x8*)(hTb + (size_t)(16 + r) * N + ks * 32 + g * 8);
        acc00 = __builtin_amdgcn_mfma_f32_16x16x32_bf16(a0f, b0, acc00, 0, 0, 0);
        acc01 = __builtin_amdgcn_mfma_f32_16x16x32_bf16(a0f, b1, acc01, 0, 0, 0);
        acc10 = __builtin_amdgcn_mfma_f32_16x16x32_bf16(a1f, b0, acc10, 0, 0, 0);
        acc11 = __builtin_amdgcn_mfma_f32_16x16x32_bf16(a1f, b1, acc11, 0, 0, 0);
      }
    }
    if (ch + 1 < NCH) COMPUTE((ch + 1) & 1);
  }

  // ---- s partials (reduce over 32 j-lanes) ----
#pragma unroll
  for (int p = 0; p < 4; p++)
#pragma unroll
    for (int h_ = 0; h_ < NH; h_++) {
      float v = sacc[p][h_];
      v += __shfl_xor(v, 16); v += __shfl_xor(v, 8);
      v += __shfl_xor(v, 4);  v += __shfl_xor(v, 2); v += __shfl_xor(v, 1);
      if (jl == 0) {
        int i = ib + ig + 8 * p;
        s_part[((size_t)sp * N + i) * NH + h_] = v;
      }
    }
  // ---- o partials ----
  {
#pragma unroll
    for (int q = 0; q < 4; q++) {
      int i0 = ib + g * 4 + q;        // M-tile 0 rows
      int i1 = ib + 16 + g * 4 + q;   // M-tile 1 rows
      float* op0 = o_part + ((size_t)sp * N + i0) * HID + wv * HD;
      float* op1 = o_part + ((size_t)sp * N + i1) * HID + wv * HD;
      op0[r] = acc00[q];
      op0[16 + r] = acc01[q];
      op1[r] = acc10[q];
      op1[16 + r] = acc11[q];
    }
  }
}

// ---------------- combine splits, divide, ELU, LayerNorm ----------------
__global__ __launch_bounds__(128) void k_combine(const float* __restrict__ o_part,
                                                 const float* __restrict__ s_part,
                                                 const float* __restrict__ g,
                                                 const float* __restrict__ b,
                                                 float* __restrict__ xout) {
  int i = blockIdx.x, c = threadIdx.x;
  float o = 0.f, s = 0.f;
#pragma unroll
  for (int sp = 0; sp < TSPLIT; sp++) {
    o += o_part[((size_t)sp * N + i) * HID + c];
    s += s_part[((size_t)sp * N + i) * NH + (c >> 5)];
  }
  float v = o / s;
  v = v > 0.f ? v : expm1f(v);
  float sm = v, sq = v * v;
  for (int off = 32; off > 0; off >>= 1) { sm += __shfl_xor(sm, off); sq += __shfl_xor(sq, off); }
  __shared__ float s2[2][2];
  int w = c >> 6, l = c & 63;
  if (l == 0) { s2[w][0] = sm; s2[w][1] = sq; }
  __syncthreads();
  float tot = s2[0][0] + s2[1][0], totq = s2[0][1] + s2[1][1];
  float mu = tot / (float)HID;
  float var = totq / (float)HID - mu * mu;
  float rs = rsqrtf(var + EPS);
  xout[(size_t)i * HID + c] = (v - mu) * rs * g[c] + b[c];
}

// ---------------- final MLP + gather ----------------
__global__ __launch_bounds__(128) void k_final(const float* __restrict__ x,
                                               const int* __restrict__ tid,
                                               const float* __restrict__ attr,
                                               const float* __restrict__ Wa,
                                               const float* __restrict__ ba,
                                               const float* __restrict__ W1,
                                               const float* __restrict__ b1,
                                               const float* __restrict__ W2,
                                               const float* __restrict__ b2,
                                               float* __restrict__ out) {
  int bI = blockIdx.x, c = threadIdx.x;
  __shared__ float tf[HID];
  __shared__ float red[2];
  int id = tid[bI];
  float av = attr[bI];
  tf[c] = x[(size_t)id * HID + c] + av * Wa[c] + ba[c];
  __syncthreads();
  float acc = b1[c];
  for (int i = 0; i < HID; i++) acc += tf[i] * W1[i * HID + c];
  acc = fmaxf(acc, 0.f);
  float pr = acc * W2[c];
  for (int off = 32; off > 0; off >>= 1) pr += __shfl_xor(pr, off);
  int w = c >> 6, l = c & 63;
  if (l == 0) red[w] = pr;
  __syncthreads();
  if (c == 0) out[bI] = red[0] + red[1] + b2[0];
}

extern "C" void kernel_launch(void* const* d_in, const int* in_sizes, int n_in,
                              void* d_out, int out_size, void* d_ws, size_t ws_size,
                              hipStream_t stream) {
  (void)in_sizes; (void)n_in; (void)out_size; (void)ws_size;
  const int*   topic_ids = (const int*)d_in[0];
  const float* adj  = (const float*)d_in[1];
  const float* tmat = (const float*)d_in[2];
  const float* attr = (const float*)d_in[3];
  const float* emb  = (const float*)d_in[4];
  const float* Ws   = (const float*)d_in[5];
  const float* bs   = (const float*)d_in[6];
  const float* Wa   = (const float*)d_in[7];
  const float* ba   = (const float*)d_in[8];
  const float* gW   = (const float*)d_in[9];
  const float* gA   = (const float*)d_in[10];
  const float* lng  = (const float*)d_in[11];
  const float* lnb  = (const float*)d_in[12];
  const float* W1   = (const float*)d_in[13];
  const float* b1   = (const float*)d_in[14];
  const float* W2   = (const float*)d_in[15];
  const float* b2   = (const float*)d_in[16];

  char* ws = (char*)d_ws;
  size_t o = 0;
  auto alloc = [&](size_t bytes) { void* p = ws + o; o += (bytes + 255) & ~255ull; return p; };
  uint*   tmax_u = (uint*)alloc(4);
  uint*   deg0   = (uint*)alloc((size_t)N * 4);
  float*  X0     = (float*)alloc((size_t)N * HID * 4);
  float*  X1     = (float*)alloc((size_t)N * HID * 4);
  float*  X2     = (float*)alloc((size_t)N * HID * 4);
  ushort* hT     = (ushort*)alloc((size_t)HID * N * 2);
  float*  es     = (float*)alloc((size_t)NH * N * 4);
  float*  ed     = (float*)alloc((size_t)NH * N * 4);
  float*  o_part = (float*)alloc((size_t)TSPLIT * N * HID * 4);
  float*  s_part = (float*)alloc((size_t)TSPLIT * N * NH * 4);
  ushort* aw     = (ushort*)alloc((size_t)N * N * 2);

  hipMemsetAsync(tmax_u, 0, 4, stream);
  k_prep1<<<1024, 256, 0, stream>>>((const float4*)tmat, tmax_u);
  k_prep2<<<N / 4, 256, 0, stream>>>(tmat, adj, tmax_u, aw, deg0);
  k_struct<<<N, 128, 0, stream>>>(emb, Ws, bs, X0);

  const float* xin = X0;
  float* xouts[2] = {X1, X2};
  for (int l = 0; l < 2; l++) {
    k_h<<<N / 8, 256, 0, stream>>>(xin, gW + (size_t)l * NH * HID * HD,
                                   gA + (size_t)l * NH * 2 * HD, hT, es, ed);
    dim3 gr(N / 32, TSPLIT);
    k_att<<<gr, 256, 0, stream>>>(aw, hT, es, ed, deg0, o_part, s_part);
    k_combine<<<N, 128, 0, stream>>>(o_part, s_part, lng + l * HID, lnb + l * HID, xouts[l]);
    xin = xouts[l];
  }
  k_final<<<NB, 128, 0, stream>>>(X2, topic_ids, attr, Wa, ba, W1, b1, W2, b2, (float*)d_out);
}